// Round 5
// baseline (1257.985 us; speedup 1.0000x reference)
//
#include <hip/hip_runtime.h>

typedef unsigned short ushort_t;
typedef __bf16 bf16x8 __attribute__((ext_vector_type(8)));
typedef __bf16 bf16x2 __attribute__((ext_vector_type(2)));
typedef float f32x4 __attribute__((ext_vector_type(4)));

#define LOG2E 1.4426950408889634f
#define LN2   0.6931471805599453f

__device__ __forceinline__ ushort_t f2bf(float f) {
    unsigned u;
    __builtin_memcpy(&u, &f, 4);
    u += 0x7fffu + ((u >> 16) & 1u);   // RNE
    return (ushort_t)(u >> 16);
}

// inputs pre-scaled by log2(e): silu2(y) = y * sigmoid2(y) = log2e*silu(x).
// Downstream weights carry the compensating ln2. Simple form (one rcp per
// silu): R4 proved the quad-batched rcp variant net-regresses (trans pipe
// is only ~25% utilized; extra VALU ops hit the binding pipe).
__device__ __forceinline__ float silu2(float y) {
    float e = __builtin_amdgcn_exp2f(-y);
    return y * __builtin_amdgcn_rcpf(1.0f + e);
}

__device__ __forceinline__ float rdlane(float v, int l) {
    return __builtin_bit_cast(float, __builtin_amdgcn_readlane(__builtin_bit_cast(int, v), l));
}

// XOR-swizzled A/B-fragment LDS layout for 16x16x32 bf16 MFMA:
// element (row,k) -> frag  = (k>>5)   [within a wave's 16-row region]
//                    slot  = ((row&15) ^ ((k>>5)&3) ^ (((k>>3)&3)<<2))
//                            + 16*((k>>3)&3)                             [16 B]
//                    byte  = (k&7)*2
// Reads: b128, 64 distinct slots, conflict-free. Writes: 2-way (free).
//
// SWAPPED-OPERAND GEMM: acc = mfma(W1frag, H0frag, acc). A- and B-fragment
// lane layouts are identical for this shape (index = lane&15, k-slice =
// (lane>>4)*8), so the same staged frags serve either operand slot. With
// W1 as A: D[m=hidden][n=edge-row] -> lane holds col=edge-row (lane&15),
// rows=hidden (q*4+r per 16-row tile). Layer-2 dot over hidden is then
// mostly in-register; cross-lane reduce is 2 shfl_xor (q-dim) instead of
// 4, idx broadcast 2 instead of 8, atomics issue from 16 parallel lanes.
//
// LDS: sW1 32 KB + sH0 16 KB (4 KB/wave) + sB1/sW2 1 KB = 49 KB ->
// 3 blocks/CU (12 waves/CU). Hot loop barrier-free: wave owns frags
// [4w,4w+4) of sH0; wave-local DS ops are in-order.
//
// __launch_bounds__(256,3): 2nd arg behaves as min BLOCKS/CU on this
// toolchain (R3: (512,4) -> 64-VGPR cap -> 1 GB spill traffic). Cap here
// is 512*4/(3*4) ~ 170 VGPR. DO NOT RAISE the 2nd arg.

// Packed scatter accumulator: one f64 atomic carries sum + 65536*count.
#define CNT_UNIT 65536.0

__global__ __launch_bounds__(256, 3) void mlp_kernel(
    const float* __restrict__ v,    // [N,3] f32
    const float* __restrict__ rij,  // [E,3] f32
    const float* __restrict__ W0,   // [128,4]
    const float* __restrict__ b0,   // [128]
    const float* __restrict__ W1,   // [128,128] (n,k)
    const float* __restrict__ b1,   // [128]
    const float* __restrict__ W2,   // [128]
    const float* __restrict__ b2,   // [1]
    const int* __restrict__ eidx,   // [2,E] int32
    double* __restrict__ acc_i, double* __restrict__ acc_j,
    int E, int nchunks)             // chunk = 64 edges (4 waves x 16)
{
    __shared__ ushort_t sW1[16384];   // 32 KB, frag layout (unswizzled)
    __shared__ ushort_t sH0[8192];    // 16 KB, XOR-swizzled; wave w owns frags [4w,4w+4)
    __shared__ float    sB1[128];     // b1 * log2e (f32)
    __shared__ float    sW2[128];     // W2 * ln2   (f32)

    const int tid  = threadIdx.x;
    const int lane = tid & 63;
    const int wave = tid >> 6;

    // ---- stage W1 (f32 -> bf16) into LDS (once per block) ----
    // W1's silu-prescale (log2e) cancels against h0' (ln2): staged UNSCALED.
    {
        int n = tid >> 1, half = tid & 1;
        const float* src = W1 + n * 128;
#pragma unroll
        for (int dk = 0; dk < 8; dk++) {
            int k0   = half * 64 + dk * 8;
            int frag = (n >> 4) * 4 + (k0 >> 5);
            int slot = (n & 15) + 16 * ((k0 >> 3) & 3);
            ushort_t tmp[8];
#pragma unroll
            for (int t = 0; t < 8; t++) tmp[t] = f2bf(src[k0 + t]);
            *(uint4*)(&sW1[frag * 512 + slot * 8]) = *(const uint4*)tmp;
        }
    }
    // ---- stage b1'/w2' (tiny) ----
    if (tid < 128) {
        sB1[tid] = b1[tid] * LOG2E;   // pre-activation scale for layer-1 silu2
        sW2[tid] = W2[tid] * LN2;     // compensates log2e in silu2 output
    }

    // ---- per-lane constants (log2e folded) ----
    float4 w0q[2]; float b0v[2];
#pragma unroll
    for (int kk = 0; kk < 2; kk++) {
        int h = 2 * lane + kk;
        w0q[kk].x = W0[h * 4 + 0] * LOG2E;
        w0q[kk].y = W0[h * 4 + 1] * LOG2E;
        w0q[kk].z = W0[h * 4 + 2] * LOG2E;
        w0q[kk].w = W0[h * 4 + 3] * LOG2E;
        b0v[kk]   = b0[h] * LOG2E;
    }
    const float b2f = b2[0];

    __syncthreads();   // sW1/sB1/sW2 ready; hot loop below is barrier-free

    const int q = lane >> 4, c = lane & 15, p = (lane >> 2) & 3, bsub = lane & 3;
    const int q4 = q * 4;
    const int ple  = lane >> 2;     // edge-in-wave this lane preloads
    const int comp = lane & 3;      // 0..2: v component, 3: |r|/H

    // ---- gather preload for one chunk (lane-parallel) ----
    auto preload = [&](int ch, float& val_o, int& idx_o) {
        float val = 0.f; int idxr = 0;
        int pe = ch * 64 + wave * 16 + ple;
        if (ch < nchunks && pe < E) {
            if (comp == 3) {
                float r0 = rij[3 * pe], r1 = rij[3 * pe + 1], r2 = rij[3 * pe + 2];
                val = sqrtf(fmaf(r0, r0, fmaf(r1, r1, r2 * r2))) * (1.0f / 3.0f);
            } else {
                int i = eidx[pe], jj = eidx[E + pe];
                idxr = (comp == 1) ? jj : i;
                val = v[3 * i + comp] - v[3 * jj + comp];
            }
        }
        val_o = val; idx_o = idxr;
    };

    float val; int idxr;
    preload(blockIdx.x, val, idxr);   // prologue load for first chunk

    for (int chunk = blockIdx.x; chunk < nchunks; chunk += gridDim.x) {
        const float val_cur = val;
        const int   idx_cur = idxr;
        // issue next chunk's gathers now; consumed one full iteration later
        preload(chunk + (int)gridDim.x, val, idxr);

        const int ebase = chunk * 64 + wave * 16;

        // ===== two temporal halves: layer0 -> 16-row LDS region -> H0 frags =====
        bf16x8 afr[2][4];
#pragma unroll
        for (int half = 0; half < 2; ++half) {
#pragma unroll
            for (int le = 0; le < 8; le++) {
                int se = half * 8 + le;
                float vx = rdlane(val_cur, se * 4 + 0);
                float vy = rdlane(val_cur, se * 4 + 1);
                float vz = rdlane(val_cur, se * 4 + 2);
                float rr = rdlane(val_cur, se * 4 + 3);
                float cc0 = fmaf(w0q[0].x, rr, b0v[0]);
                float dd0 = fmaf(w0q[0].y, vx, fmaf(w0q[0].z, vy, w0q[0].w * vz));
                float cc1 = fmaf(w0q[1].x, rr, b0v[1]);
                float dd1 = fmaf(w0q[1].y, vx, fmaf(w0q[1].z, vy, w0q[1].w * vz));
                float s0 = silu2(cc0 + dd0);   // x_i, h=2l
                float s1 = silu2(cc0 - dd0);   // x_j, h=2l
                float s2 = silu2(cc1 + dd1);   // x_i, h=2l+1
                float s3 = silu2(cc1 - dd1);   // x_j, h=2l+1
                bf16x2 pki, pkj;
                pki[0] = (__bf16)s0; pki[1] = (__bf16)s2;
                pkj[0] = (__bf16)s1; pkj[1] = (__bf16)s3;
                int mi = 2 * le;                  // x_i row in [0,16); x_j row = mi+1
                int fr = wave * 4 + q;
                int sli = ((mi ^ q ^ (p << 2)) & 15) + (p << 4);
                int slj = (((mi + 1) ^ q ^ (p << 2)) & 15) + (p << 4);
                ((unsigned*)sH0)[fr * 256 + sli * 4 + bsub] = __builtin_bit_cast(unsigned, pki);
                ((unsigned*)sH0)[fr * 256 + slj * 4 + bsub] = __builtin_bit_cast(unsigned, pkj);
            }
            // cache this half's H0 fragments before half 1 overwrites the region
#pragma unroll
            for (int ks = 0; ks < 4; ks++) {
                int sl_rd = (((lane & 15) ^ ks ^ (q << 2)) & 15) + 16 * q;
                afr[half][ks] = *(const bf16x8*)(&sH0[(wave * 4 + ks) * 512 + sl_rd * 8]);
            }
        }

        // ===== GEMM (swapped): acc[mt][et] = W1tile(mt) x H0tile(et) + b1' =====
        // D[m=hidden][n=edge-row]: lane holds edge-row = et*16+c, hidden rows
        // mt*16 + q4 + r. acc init = b1' broadcast (edge-independent).
        f32x4 acc[8][2];
#pragma unroll
        for (int mt = 0; mt < 8; mt++) {
            f32x4 bq = *(const f32x4*)(&sB1[mt * 16 + q4]);
            acc[mt][0] = bq;
            acc[mt][1] = bq;
        }

#pragma unroll
        for (int ks = 0; ks < 4; ks++) {
#pragma unroll
            for (int mt = 0; mt < 8; mt++) {
                bf16x8 bb = *(const bf16x8*)(&sW1[(mt * 4 + ks) * 512 + lane * 8]);
                acc[mt][0] = __builtin_amdgcn_mfma_f32_16x16x32_bf16(bb, afr[0][ks], acc[mt][0], 0, 0, 0);
                acc[mt][1] = __builtin_amdgcn_mfma_f32_16x16x32_bf16(bb, afr[1][ks], acc[mt][1], 0, 0, 0);
            }
        }

        // ===== epilogue: silu2(h1') . w2' summed in-register over hidden =====
        float rs0 = 0.f, rs1 = 0.f;
#pragma unroll
        for (int mt = 0; mt < 8; mt++) {
            f32x4 wq = *(const f32x4*)(&sW2[mt * 16 + q4]);
#pragma unroll
            for (int r = 0; r < 4; r++) {
                rs0 = fmaf(silu2(acc[mt][0][r]), wq[r], rs0);
                rs1 = fmaf(silu2(acc[mt][1][r]), wq[r], rs1);
            }
        }
        // reduce across q (lanes c, c+16, c+32, c+48) -> full sum per edge-row
#pragma unroll
        for (int et = 0; et < 2; et++) {
            float s = et ? rs1 : rs0;
            s += __shfl_xor(s, 16, 64);
            s += __shfl_xor(s, 32, 64);
            int er   = et * 16 + c;                       // edge-row in [0,32)
            int node = __shfl(idx_cur, (er >> 1) * 4 + (er & 1), 64);
            int e    = ebase + (er >> 1);
            if (q == 0 && e < E) {
                double contrib = (double)(s + b2f) + CNT_UNIT;
                double* dst = (er & 1) ? acc_j : acc_i;   // odd row = x_j teacher
                atomicAdd(&dst[node], contrib);
            }
        }
        // wave-local LDS WAR across chunks is safe: one wave's DS ops are in-order.
    }
}

__global__ void finalize_kernel(const double* __restrict__ acc_i,
                                const double* __restrict__ acc_j,
                                float* __restrict__ out, int N)
{
    int n = blockIdx.x * 256 + threadIdx.x;
    if (n < N) {
        double ti = acc_i[n], tj = acc_j[n];
        double ci = rint(ti * (1.0 / CNT_UNIT));
        double cj = rint(tj * (1.0 / CNT_UNIT));
        double si = ti - ci * CNT_UNIT;
        double sj = tj - cj * CNT_UNIT;
        out[n] = (float)(si / fmax(ci, 1.0) + sj / fmax(cj, 1.0));
    }
}

extern "C" void kernel_launch(void* const* d_in, const int* in_sizes, int n_in,
                              void* d_out, int out_size, void* d_ws, size_t ws_size,
                              hipStream_t stream) {
    const float* v   = (const float*)d_in[0];
    const float* rij = (const float*)d_in[1];
    const float* W0  = (const float*)d_in[2];
    const float* b0  = (const float*)d_in[3];
    const float* W1  = (const float*)d_in[4];
    const float* b1  = (const float*)d_in[5];
    const float* W2  = (const float*)d_in[6];
    const float* b2  = (const float*)d_in[7];
    const int* eidx  = (const int*)d_in[8];

    const int E = in_sizes[1] / 3;
    const int N = out_size;

    double* acc_i = (double*)d_ws;
    double* acc_j = acc_i + N;

    hipMemsetAsync(d_ws, 0, (size_t)2 * N * sizeof(double), stream);

    int nchunks = (E + 63) / 64;
    int grid = nchunks < 768 ? nchunks : 768;
    mlp_kernel<<<grid, 256, 0, stream>>>(v, rij, W0, b0, W1, b1, W2, b2, eidx,
                                         acc_i, acc_j, E, nchunks);
    finalize_kernel<<<(N + 255) / 256, 256, 0, stream>>>(acc_i, acc_j,
                                                         (float*)d_out, N);
}

// Round 6
// 655.601 us; speedup vs baseline: 1.9188x; 1.9188x over previous
//
#include <hip/hip_runtime.h>

typedef unsigned short ushort_t;
typedef __bf16 bf16x8 __attribute__((ext_vector_type(8)));
typedef __bf16 bf16x2 __attribute__((ext_vector_type(2)));
typedef float f32x4 __attribute__((ext_vector_type(4)));

#define LOG2E 1.4426950408889634f
#define LN2   0.6931471805599453f

__device__ __forceinline__ ushort_t f2bf(float f) {
    unsigned u;
    __builtin_memcpy(&u, &f, 4);
    u += 0x7fffu + ((u >> 16) & 1u);   // RNE
    return (ushort_t)(u >> 16);
}

// inputs pre-scaled by log2(e): silu2(y) = y * sigmoid2(y) = log2e*silu(x).
// Downstream weights carry the compensating ln2. Simple form (one rcp per
// silu): R4 proved the quad-batched rcp variant net-regresses (trans pipe
// is only ~25% utilized; extra VALU ops hit the binding pipe).
__device__ __forceinline__ float silu2(float y) {
    float e = __builtin_amdgcn_exp2f(-y);
    return y * __builtin_amdgcn_rcpf(1.0f + e);
}

__device__ __forceinline__ float rdlane(float v, int l) {
    return __builtin_bit_cast(float, __builtin_amdgcn_readlane(__builtin_bit_cast(int, v), l));
}

// XOR-swizzled A/B-fragment LDS layout for 16x16x32 bf16 MFMA:
// element (row,k) -> frag  = (k>>5)   [within a wave's 16-row region]
//                    slot  = ((row&15) ^ ((k>>5)&3) ^ (((k>>3)&3)<<2))
//                            + 16*((k>>3)&3)                             [16 B]
//                    byte  = (k&7)*2
// Reads: b128, 64 distinct slots, conflict-free. Writes: 2-way (free).
//
// SWAPPED-OPERAND GEMM (verified R5, absmax unchanged): acc = mfma(W1frag,
// H0frag, acc) -> D[m=hidden][n=edge-row]; lane holds edge-row = lane&15,
// hidden rows q*4+r per 16-row tile. Layer-2 dot over hidden is mostly
// in-register; q-dim reduce is 2 shfl_xor; atomics issue from 16 lanes.
//
// R5 LESSON (spill disaster, 3.3 GB scratch FETCH): mt-indexed acc[8][2]
// (64 regs) live across the whole GEMM + afr (32 regs) exceeds what the
// allocator will keep resident -> it spilled acc per chunk. FIX: mt is the
// OUTER loop; per mt only 2 f32x4 accumulators live (8 regs), consumed by
// the epilogue immediately. Spill watch: FETCH_SIZE, not just VGPR_Count.
//
// LDS: sW1 32 KB + sH0 16 KB (4 KB/wave) + sB1/sW2 1 KB = 49 KB ->
// 3 blocks/CU (12 waves/CU). Hot loop barrier-free: wave owns frags
// [4w,4w+4) of sH0; wave-local DS ops are in-order.
//
// __launch_bounds__(256,3): 2nd arg behaves as min BLOCKS/CU on this
// toolchain (R3: (512,4) -> 64-VGPR cap -> 1 GB spill traffic). DO NOT
// RAISE the 2nd arg.

// Packed scatter accumulator: one f64 atomic carries sum + 65536*count.
#define CNT_UNIT 65536.0

__global__ __launch_bounds__(256, 3) void mlp_kernel(
    const float* __restrict__ v,    // [N,3] f32
    const float* __restrict__ rij,  // [E,3] f32
    const float* __restrict__ W0,   // [128,4]
    const float* __restrict__ b0,   // [128]
    const float* __restrict__ W1,   // [128,128] (n,k)
    const float* __restrict__ b1,   // [128]
    const float* __restrict__ W2,   // [128]
    const float* __restrict__ b2,   // [1]
    const int* __restrict__ eidx,   // [2,E] int32
    double* __restrict__ acc_i, double* __restrict__ acc_j,
    int E, int nchunks)             // chunk = 64 edges (4 waves x 16)
{
    __shared__ ushort_t sW1[16384];   // 32 KB, frag layout (unswizzled)
    __shared__ ushort_t sH0[8192];    // 16 KB, XOR-swizzled; wave w owns frags [4w,4w+4)
    __shared__ float    sB1[128];     // b1 * log2e (f32)
    __shared__ float    sW2[128];     // W2 * ln2   (f32)

    const int tid  = threadIdx.x;
    const int lane = tid & 63;
    const int wave = tid >> 6;

    // ---- stage W1 (f32 -> bf16) into LDS (once per block) ----
    // W1's silu-prescale (log2e) cancels against h0' (ln2): staged UNSCALED.
    {
        int n = tid >> 1, half = tid & 1;
        const float* src = W1 + n * 128;
#pragma unroll
        for (int dk = 0; dk < 8; dk++) {
            int k0   = half * 64 + dk * 8;
            int frag = (n >> 4) * 4 + (k0 >> 5);
            int slot = (n & 15) + 16 * ((k0 >> 3) & 3);
            ushort_t tmp[8];
#pragma unroll
            for (int t = 0; t < 8; t++) tmp[t] = f2bf(src[k0 + t]);
            *(uint4*)(&sW1[frag * 512 + slot * 8]) = *(const uint4*)tmp;
        }
    }
    // ---- stage b1'/w2' (tiny) ----
    if (tid < 128) {
        sB1[tid] = b1[tid] * LOG2E;   // pre-activation scale for layer-1 silu2
        sW2[tid] = W2[tid] * LN2;     // compensates log2e in silu2 output
    }

    // ---- per-lane constants (log2e folded) ----
    float4 w0q[2]; float b0v[2];
#pragma unroll
    for (int kk = 0; kk < 2; kk++) {
        int h = 2 * lane + kk;
        w0q[kk].x = W0[h * 4 + 0] * LOG2E;
        w0q[kk].y = W0[h * 4 + 1] * LOG2E;
        w0q[kk].z = W0[h * 4 + 2] * LOG2E;
        w0q[kk].w = W0[h * 4 + 3] * LOG2E;
        b0v[kk]   = b0[h] * LOG2E;
    }
    const float b2f = b2[0];

    __syncthreads();   // sW1/sB1/sW2 ready; hot loop below is barrier-free

    const int q = lane >> 4, c = lane & 15, p = (lane >> 2) & 3, bsub = lane & 3;
    const int q4 = q * 4;
    const int ple  = lane >> 2;     // edge-in-wave this lane preloads
    const int comp = lane & 3;      // 0..2: v component, 3: |r|/H

    // ---- gather preload for one chunk (lane-parallel) ----
    auto preload = [&](int ch, float& val_o, int& idx_o) {
        float val = 0.f; int idxr = 0;
        int pe = ch * 64 + wave * 16 + ple;
        if (ch < nchunks && pe < E) {
            if (comp == 3) {
                float r0 = rij[3 * pe], r1 = rij[3 * pe + 1], r2 = rij[3 * pe + 2];
                val = sqrtf(fmaf(r0, r0, fmaf(r1, r1, r2 * r2))) * (1.0f / 3.0f);
            } else {
                int i = eidx[pe], jj = eidx[E + pe];
                idxr = (comp == 1) ? jj : i;
                val = v[3 * i + comp] - v[3 * jj + comp];
            }
        }
        val_o = val; idx_o = idxr;
    };

    float val; int idxr;
    preload(blockIdx.x, val, idxr);   // prologue load for first chunk

    for (int chunk = blockIdx.x; chunk < nchunks; chunk += gridDim.x) {
        const float val_cur = val;
        const int   idx_cur = idxr;
        // issue next chunk's gathers now; consumed one full iteration later
        preload(chunk + (int)gridDim.x, val, idxr);

        const int ebase = chunk * 64 + wave * 16;

        // ===== two temporal halves: layer0 -> 16-row LDS region -> H0 frags =====
        bf16x8 afr[2][4];
#pragma unroll
        for (int half = 0; half < 2; ++half) {
#pragma unroll
            for (int le = 0; le < 8; le++) {
                int se = half * 8 + le;
                float vx = rdlane(val_cur, se * 4 + 0);
                float vy = rdlane(val_cur, se * 4 + 1);
                float vz = rdlane(val_cur, se * 4 + 2);
                float rr = rdlane(val_cur, se * 4 + 3);
                float cc0 = fmaf(w0q[0].x, rr, b0v[0]);
                float dd0 = fmaf(w0q[0].y, vx, fmaf(w0q[0].z, vy, w0q[0].w * vz));
                float cc1 = fmaf(w0q[1].x, rr, b0v[1]);
                float dd1 = fmaf(w0q[1].y, vx, fmaf(w0q[1].z, vy, w0q[1].w * vz));
                float s0 = silu2(cc0 + dd0);   // x_i, h=2l
                float s1 = silu2(cc0 - dd0);   // x_j, h=2l
                float s2 = silu2(cc1 + dd1);   // x_i, h=2l+1
                float s3 = silu2(cc1 - dd1);   // x_j, h=2l+1
                bf16x2 pki, pkj;
                pki[0] = (__bf16)s0; pki[1] = (__bf16)s2;
                pkj[0] = (__bf16)s1; pkj[1] = (__bf16)s3;
                int mi = 2 * le;                  // x_i row in [0,16); x_j row = mi+1
                int fr = wave * 4 + q;
                int sli = ((mi ^ q ^ (p << 2)) & 15) + (p << 4);
                int slj = (((mi + 1) ^ q ^ (p << 2)) & 15) + (p << 4);
                ((unsigned*)sH0)[fr * 256 + sli * 4 + bsub] = __builtin_bit_cast(unsigned, pki);
                ((unsigned*)sH0)[fr * 256 + slj * 4 + bsub] = __builtin_bit_cast(unsigned, pkj);
            }
            // cache this half's H0 fragments before half 1 overwrites the region
#pragma unroll
            for (int ks = 0; ks < 4; ks++) {
                int sl_rd = (((lane & 15) ^ ks ^ (q << 2)) & 15) + 16 * q;
                afr[half][ks] = *(const bf16x8*)(&sH0[(wave * 4 + ks) * 512 + sl_rd * 8]);
            }
        }

        // ===== fused GEMM+epilogue, mt OUTER (acc live range = one mt) =====
        // per mt: a0/a1 = b1'(bcast) + W1tile(mt) x H0tile(et), then
        // rs += silu2(a) . w2' immediately. Only 8 acc regs live at a time.
        float rs0 = 0.f, rs1 = 0.f;
#pragma unroll
        for (int mt = 0; mt < 8; mt++) {
            f32x4 bq = *(const f32x4*)(&sB1[mt * 16 + q4]);
            f32x4 a0 = bq, a1 = bq;
#pragma unroll
            for (int ks = 0; ks < 4; ks++) {
                bf16x8 bb = *(const bf16x8*)(&sW1[(mt * 4 + ks) * 512 + lane * 8]);
                a0 = __builtin_amdgcn_mfma_f32_16x16x32_bf16(bb, afr[0][ks], a0, 0, 0, 0);
                a1 = __builtin_amdgcn_mfma_f32_16x16x32_bf16(bb, afr[1][ks], a1, 0, 0, 0);
            }
            f32x4 wq = *(const f32x4*)(&sW2[mt * 16 + q4]);
#pragma unroll
            for (int r = 0; r < 4; r++) {
                rs0 = fmaf(silu2(a0[r]), wq[r], rs0);
                rs1 = fmaf(silu2(a1[r]), wq[r], rs1);
            }
        }

        // reduce across q (lanes c, c+16, c+32, c+48) -> full sum per edge-row
#pragma unroll
        for (int et = 0; et < 2; et++) {
            float s = et ? rs1 : rs0;
            s += __shfl_xor(s, 16, 64);
            s += __shfl_xor(s, 32, 64);
            int er   = et * 16 + c;                       // edge-row in [0,32)
            int node = __shfl(idx_cur, (er >> 1) * 4 + (er & 1), 64);
            int e    = ebase + (er >> 1);
            if (q == 0 && e < E) {
                double contrib = (double)(s + b2f) + CNT_UNIT;
                double* dst = (er & 1) ? acc_j : acc_i;   // odd row = x_j teacher
                atomicAdd(&dst[node], contrib);
            }
        }
        // wave-local LDS WAR across chunks is safe: one wave's DS ops are in-order.
    }
}

__global__ void finalize_kernel(const double* __restrict__ acc_i,
                                const double* __restrict__ acc_j,
                                float* __restrict__ out, int N)
{
    int n = blockIdx.x * 256 + threadIdx.x;
    if (n < N) {
        double ti = acc_i[n], tj = acc_j[n];
        double ci = rint(ti * (1.0 / CNT_UNIT));
        double cj = rint(tj * (1.0 / CNT_UNIT));
        double si = ti - ci * CNT_UNIT;
        double sj = tj - cj * CNT_UNIT;
        out[n] = (float)(si / fmax(ci, 1.0) + sj / fmax(cj, 1.0));
    }
}

extern "C" void kernel_launch(void* const* d_in, const int* in_sizes, int n_in,
                              void* d_out, int out_size, void* d_ws, size_t ws_size,
                              hipStream_t stream) {
    const float* v   = (const float*)d_in[0];
    const float* rij = (const float*)d_in[1];
    const float* W0  = (const float*)d_in[2];
    const float* b0  = (const float*)d_in[3];
    const float* W1  = (const float*)d_in[4];
    const float* b1  = (const float*)d_in[5];
    const float* W2  = (const float*)d_in[6];
    const float* b2  = (const float*)d_in[7];
    const int* eidx  = (const int*)d_in[8];

    const int E = in_sizes[1] / 3;
    const int N = out_size;

    double* acc_i = (double*)d_ws;
    double* acc_j = acc_i + N;

    hipMemsetAsync(d_ws, 0, (size_t)2 * N * sizeof(double), stream);

    int nchunks = (E + 63) / 64;
    int grid = nchunks < 768 ? nchunks : 768;
    mlp_kernel<<<grid, 256, 0, stream>>>(v, rij, W0, b0, W1, b1, W2, b2, eidx,
                                         acc_i, acc_j, E, nchunks);
    finalize_kernel<<<(N + 255) / 256, 256, 0, stream>>>(acc_i, acc_j,
                                                         (float*)d_out, N);
}